// Round 9
// baseline (422.388 us; speedup 1.0000x reference)
//
#include <hip/hip_runtime.h>
#include <math.h>

#define NND 65536   // total nodes
#define NPER 512    // nodes per graph
#define NGR 128     // graphs (B)
#define DD 128      // feature dim
#define NED 524288  // edges

typedef __attribute__((ext_vector_type(8))) short short8;
typedef __attribute__((ext_vector_type(4))) float f32x4;

__device__ __forceinline__ unsigned short f2b(float f) {
  unsigned u = __float_as_uint(f);
  return (unsigned short)((u + 0x7FFFu + ((u >> 16) & 1u)) >> 16);
}
__device__ __forceinline__ float b2f(unsigned short h) {
  return __uint_as_float(((unsigned)h) << 16);
}

// ---------------- CSR build ----------------

__global__ __launch_bounds__(256) void init_kernel(int* __restrict__ counts,
                                                   float2* __restrict__ tm) {
  int i = blockIdx.x * 256 + threadIdx.x;
  counts[i] = 0;
  tm[i] = make_float2(1.f, 1.f);  // layer-0: all selected, t=1
}

__global__ __launch_bounds__(256) void hist_kernel(const int* __restrict__ ei,
                                                   int* __restrict__ counts) {
  int e = blockIdx.x * 256 + threadIdx.x;
  atomicAdd(&counts[ei[NED + e]], 1);
}

__global__ __launch_bounds__(1024) void scan_kernel(const int* __restrict__ counts,
                                                    int* __restrict__ off,
                                                    int* __restrict__ cursor) {
  __shared__ int part[1024];
  int t = threadIdx.x;
  int base = t * 64;
  int s = 0;
  const int4* c4 = (const int4*)(counts + base);
  for (int i = 0; i < 16; ++i) {
    int4 v = c4[i];
    s += v.x + v.y + v.z + v.w;
  }
  part[t] = s;
  __syncthreads();
  for (int d = 1; d < 1024; d <<= 1) {
    int v = (t >= d) ? part[t - d] : 0;
    __syncthreads();
    part[t] += v;
    __syncthreads();
  }
  int run = (t == 0) ? 0 : part[t - 1];
  for (int i = 0; i < 64; ++i) {
    off[base + i] = run;
    cursor[base + i] = run;
    run += counts[base + i];
  }
  if (t == 1023) off[NND] = run;
}

__global__ __launch_bounds__(256) void scatter_kernel(const int* __restrict__ ei,
                                                      int* __restrict__ cursor,
                                                      int* __restrict__ ssrc) {
  int e = blockIdx.x * 256 + threadIdx.x;
  int dst = ei[NED + e];
  int pos = atomicAdd(&cursor[dst], 1);
  ssrc[pos] = ei[e];
}

// ---------------- weight prep: bf16 hi/lo in MFMA-FRAGMENT order ----------------

__global__ __launch_bounds__(256) void prepw_kernel(
    const float* __restrict__ wl0, const float* __restrict__ wr0,
    const float* __restrict__ wl1, const float* __restrict__ wr1,
    const float* __restrict__ wl2, const float* __restrict__ wr2,
    unsigned short* __restrict__ Whi, unsigned short* __restrict__ Wlo) {
  const float* wls[3] = {wl0, wl1, wl2};
  const float* wrs[3] = {wr0, wr1, wr2};
  int e = blockIdx.x * 256 + threadIdx.x;  // 3*32768
  int l = e >> 15;
  int o = e & 32767;
  int j = o & 7;
  int lane = (o >> 3) & 63;
  int nt = (o >> 9) & 7;
  int kc = o >> 12;
  int li = lane & 15, q = lane >> 4;
  int n = nt * 16 + li;
  int k = kc * 32 + q * 8 + j;
  const float* src = (k < 128) ? wls[l] : wrs[l];
  float v = src[n * DD + (k & 127)];
  unsigned short hi = f2b(v);
  float lo = v - b2f(hi);
  Whi[e] = hi;
  Wlo[e] = f2b(lo);
}

// ---------------- FUSED layer: agg (-> LDS) + MFMA bf16x3 GEMM + score ----------------
// Phase A: each block aggregates its 64 dst rows into smean[64][132] (fp32,
//   stride 132 -> conflict-free float4 writes, optimal b128 reads). 4 dsts per
//   wave-group with shared coalesced edge window (R8 structure), 4 groups/wave.
//   Dead dsts -> zero rows (NaN hygiene; t=0 srcs contribute 0).
// Phase B: h = relu([mean | t.*x] @ W + bl) with mean staged from LDS and
//   Ax from global (t-scaled); B fragment-ordered from global (no LDS).
//   Score epilogue -> sraw.
// XCD swizzle: a graph's 8 blocks share one XCD for gather L2 locality.

#define GBM 64
#define SMSTR 132

template <int FIRST>
__global__ __launch_bounds__(256) void layer_kernel_t(
    const float* __restrict__ x, const float2* __restrict__ tm,
    const int* __restrict__ off, const int* __restrict__ ssrc,
    const unsigned short* __restrict__ Whi, const unsigned short* __restrict__ Wlo,
    const float* __restrict__ bias, const float* __restrict__ pw,
    float* __restrict__ outp, float* __restrict__ sraw) {
  __shared__ float smean[GBM * SMSTR];  // 33.8 KB
  __shared__ short Ah[2048];            // fragment-ordered A tile (hi)
  __shared__ short Al[2048];            // (lo)
  __shared__ float s_sp[4][GBM];
  const int tid = threadIdx.x;
  const int wv = tid >> 6;
  const int lane = tid & 63;
  const int half = lane >> 5;
  const int l = lane & 31;
  const int q = lane >> 4;
  const int li = lane & 15;
  // 1024 blocks = 8 xcd * 16 graphs * 8 tiles
  const int bid = blockIdx.x;
  const int xcd = bid & 7;
  const int slot = bid >> 3;                 // 0..127
  const int graph = xcd * 16 + (slot >> 3);  // 0..127
  const int mtile = slot & 7;                // 0..7
  const int row0 = graph * NPER + mtile * GBM;

  // ---------------- Phase A: aggregate 64 rows into smean ----------------
  for (int dg = 0; dg < 4; ++dg) {
    const int d0 = row0 + wv * 16 + dg * 4;
    int offv = 0;
    if (lane < 5) offv = off[d0 + lane];
    float deadv = 1.f;
    if (!FIRST && lane < 4) deadv = tm[d0 + lane].x;
    const int b0 = __shfl(offv, 0);
    const int b1 = __shfl(offv, 1);
    const int b2 = __shfl(offv, 2);
    const int b3 = __shfl(offv, 3);
    const int e3 = __shfl(offv, 4);
    float dd[4];
    if (!FIRST) {
      dd[0] = __shfl(deadv, 0);
      dd[1] = __shfl(deadv, 1);
      dd[2] = __shfl(deadv, 2);
      dd[3] = __shfl(deadv, 3);
    }
    const int begs[4] = {b0, b1, b2, b3};
    const int ends[4] = {b1, b2, b3, e3};

    float4 acc[4];
    int deg[4];
#pragma unroll
    for (int d = 0; d < 4; ++d) {
      acc[d] = make_float4(0.f, 0.f, 0.f, 0.f);
      deg[d] = 0;
    }

    for (int base = b0; base < e3; base += 64) {
      const int nwin = min(64, e3 - base);
      int sv = 0;
      float tv = 0.f;
      int live = 0;
      if (lane < nwin) {
        sv = ssrc[base + lane];
        if (!FIRST) {
          const float2 mt = tm[sv];
          live = (mt.x != 0.f);
          tv = mt.y;
        }
      }
      unsigned long long bl;
      if (!FIRST)
        bl = __ballot(live);
      else
        bl = (nwin == 64) ? ~0ull : ((1ull << nwin) - 1);

#pragma unroll
      for (int d = 0; d < 4; ++d) {
        if (!FIRST && dd[d] == 0.f) continue;
        const int lo = max(begs[d], base);
        const int hi = min(ends[d], base + 64);
        if (lo >= hi) continue;
        const int j0 = lo - base;
        const int j1 = hi - base;
        const unsigned long long wm =
            (((j1 == 64) ? ~0ull : ((1ull << j1) - 1)) & ~((1ull << j0) - 1));
        deg[d] += (int)__popcll(bl & wm);
        int j = j0 + half;
        for (; j + 6 < j1; j += 8) {
          const int s0 = __shfl(sv, j);
          const int s1 = __shfl(sv, j + 2);
          const int s2 = __shfl(sv, j + 4);
          const int s3 = __shfl(sv, j + 6);
          const float4 v0 = *(const float4*)(x + (size_t)s0 * DD + l * 4);
          const float4 v1 = *(const float4*)(x + (size_t)s1 * DD + l * 4);
          const float4 v2 = *(const float4*)(x + (size_t)s2 * DD + l * 4);
          const float4 v3 = *(const float4*)(x + (size_t)s3 * DD + l * 4);
          if (!FIRST) {
            const float t0 = __shfl(tv, j), t1 = __shfl(tv, j + 2);
            const float t2 = __shfl(tv, j + 4), t3 = __shfl(tv, j + 6);
            acc[d].x += v0.x * t0 + v1.x * t1 + v2.x * t2 + v3.x * t3;
            acc[d].y += v0.y * t0 + v1.y * t1 + v2.y * t2 + v3.y * t3;
            acc[d].z += v0.z * t0 + v1.z * t1 + v2.z * t2 + v3.z * t3;
            acc[d].w += v0.w * t0 + v1.w * t1 + v2.w * t2 + v3.w * t3;
          } else {
            acc[d].x += v0.x + v1.x + v2.x + v3.x;
            acc[d].y += v0.y + v1.y + v2.y + v3.y;
            acc[d].z += v0.z + v1.z + v2.z + v3.z;
            acc[d].w += v0.w + v1.w + v2.w + v3.w;
          }
        }
        for (; j < j1; j += 2) {
          const int s = __shfl(sv, j);
          const float4 v = *(const float4*)(x + (size_t)s * DD + l * 4);
          if (!FIRST) {
            const float t = __shfl(tv, j);
            acc[d].x += v.x * t;
            acc[d].y += v.y * t;
            acc[d].z += v.z * t;
            acc[d].w += v.w * t;
          } else {
            acc[d].x += v.x;
            acc[d].y += v.y;
            acc[d].z += v.z;
            acc[d].w += v.w;
          }
        }
      }
    }

#pragma unroll
    for (int d = 0; d < 4; ++d) {
      float4 a = acc[d];
      const int dead = (!FIRST && dd[d] == 0.f);
      a.x += __shfl(a.x, lane ^ 32);
      a.y += __shfl(a.y, lane ^ 32);
      a.z += __shfl(a.z, lane ^ 32);
      a.w += __shfl(a.w, lane ^ 32);
      if (lane < 32) {
        const float inv = dead ? 0.f : (1.f / (float)max(deg[d], 1));
        float4 m;
        m.x = a.x * inv;
        m.y = a.y * inv;
        m.z = a.z * inv;
        m.w = a.w * inv;
        *(float4*)(smean + (wv * 16 + dg * 4 + d) * SMSTR + l * 4) = m;
      }
    }
  }
  __syncthreads();

  // ---------------- Phase B: GEMM ----------------
  int sdst[2];
  float ts[2];
#pragma unroll
  for (int i = 0; i < 2; ++i) {
    const int id = tid + i * 256;
    const int r = id >> 3;
    const int kb = (id & 7) << 2;
    sdst[i] = ((r >> 4) * 64 + (kb >> 3) * 16 + (r & 15)) * 8 + (kb & 7);
    ts[i] = FIRST ? 1.f : tm[row0 + r].y;
  }

  f32x4 acc[4][2];
#pragma unroll
  for (int m = 0; m < 4; ++m)
#pragma unroll
    for (int n = 0; n < 2; ++n) acc[m][n] = (f32x4){0.f, 0.f, 0.f, 0.f};

  float4 pa[2];
  short8 pbh[2], pbl[2];

#define LOADA(KC)                                                                       \
  {                                                                                     \
    if ((KC) < 4) {                                                                     \
      const int cb = (KC)*32;                                                           \
      _Pragma("unroll") for (int i = 0; i < 2; ++i) {                                   \
        const int id = tid + i * 256;                                                   \
        pa[i] = *(const float4*)(smean + (id >> 3) * SMSTR + cb + ((id & 7) << 2));     \
      }                                                                                 \
    } else {                                                                            \
      const int cb = ((KC)&3) * 32;                                                     \
      _Pragma("unroll") for (int i = 0; i < 2; ++i) {                                   \
        const int id = tid + i * 256;                                                   \
        pa[i] = *(const float4*)(x + (size_t)(row0 + (id >> 3)) * DD + cb + ((id & 7) << 2)); \
        if (!FIRST) {                                                                   \
          pa[i].x *= ts[i]; pa[i].y *= ts[i]; pa[i].z *= ts[i]; pa[i].w *= ts[i];       \
        }                                                                               \
      }                                                                                 \
    }                                                                                   \
  }
#define LOADB(KC)                                                                       \
  {                                                                                     \
    _Pragma("unroll") for (int n = 0; n < 2; ++n) {                                     \
      const int ga = (((KC)*8 + wv * 2 + n) * 64 + lane) * 8;                           \
      pbh[n] = *(const short8*)(Whi + ga);                                              \
      pbl[n] = *(const short8*)(Wlo + ga);                                              \
    }                                                                                   \
  }

  LOADA(0) LOADB(0)

#pragma unroll
  for (int kc = 0; kc < 8; ++kc) {
#pragma unroll
    for (int i = 0; i < 2; ++i) {
      ushort4 hv, lv;
      hv.x = f2b(pa[i].x); lv.x = f2b(pa[i].x - b2f(hv.x));
      hv.y = f2b(pa[i].y); lv.y = f2b(pa[i].y - b2f(hv.y));
      hv.z = f2b(pa[i].z); lv.z = f2b(pa[i].z - b2f(hv.z));
      hv.w = f2b(pa[i].w); lv.w = f2b(pa[i].w - b2f(hv.w));
      *(ushort4*)(Ah + sdst[i]) = hv;
      *(ushort4*)(Al + sdst[i]) = lv;
    }
    short8 bh[2], bl[2];
    bh[0] = pbh[0]; bh[1] = pbh[1];
    bl[0] = pbl[0]; bl[1] = pbl[1];
    __syncthreads();
    short8 ah[4], al[4];
#pragma unroll
    for (int m = 0; m < 4; ++m) {
      ah[m] = *(const short8*)(Ah + (m * 64 + lane) * 8);
      al[m] = *(const short8*)(Al + (m * 64 + lane) * 8);
    }
    switch (kc) {  // prefetch overlaps MFMA below
      case 0: LOADA(1) LOADB(1) break;
      case 1: LOADA(2) LOADB(2) break;
      case 2: LOADA(3) LOADB(3) break;
      case 3: LOADA(4) LOADB(4) break;
      case 4: LOADA(5) LOADB(5) break;
      case 5: LOADA(6) LOADB(6) break;
      case 6: LOADA(7) LOADB(7) break;
      default: break;
    }
#pragma unroll
    for (int m = 0; m < 4; ++m)
#pragma unroll
      for (int n = 0; n < 2; ++n) {
        acc[m][n] = __builtin_amdgcn_mfma_f32_16x16x32_bf16(ah[m], bh[n], acc[m][n], 0, 0, 0);
        acc[m][n] = __builtin_amdgcn_mfma_f32_16x16x32_bf16(ah[m], bl[n], acc[m][n], 0, 0, 0);
        acc[m][n] = __builtin_amdgcn_mfma_f32_16x16x32_bf16(al[m], bh[n], acc[m][n], 0, 0, 0);
      }
    __syncthreads();
  }
#undef LOADA
#undef LOADB

  // epilogue: bias+relu, store h (unscaled), fused score partials
  const int c0 = wv * 32 + li;
  const int c1 = wv * 32 + 16 + li;
  const float b0 = bias[c0], b1 = bias[c1];
  const float p0 = pw[c0], p1 = pw[c1];
  float sp[16];
#pragma unroll
  for (int m = 0; m < 4; ++m) {
#pragma unroll
    for (int i = 0; i < 4; ++i) {
      const int r = row0 + m * 16 + q * 4 + i;
      const float v0 = fmaxf(acc[m][0][i] + b0, 0.f);
      const float v1 = fmaxf(acc[m][1][i] + b1, 0.f);
      outp[(size_t)r * DD + c0] = v0;
      outp[(size_t)r * DD + c1] = v1;
      sp[m * 4 + i] = v0 * p0 + v1 * p1;
    }
  }
#pragma unroll
  for (int e = 0; e < 16; ++e) {
    sp[e] += __shfl_xor(sp[e], 1);
    sp[e] += __shfl_xor(sp[e], 2);
    sp[e] += __shfl_xor(sp[e], 4);
    sp[e] += __shfl_xor(sp[e], 8);
  }
  if (li == 0) {
#pragma unroll
    for (int e = 0; e < 16; ++e) s_sp[wv][(e >> 2) * 16 + q * 4 + (e & 3)] = sp[e];
  }
  __syncthreads();
  if (tid < GBM)
    sraw[row0 + tid] = s_sp[0][tid] + s_sp[1][tid] + s_sp[2][tid] + s_sp[3][tid];
}

// ---------------- topk + readout partials (h is read-only) ----------------

__global__ __launch_bounds__(256) void pool_kernel(const float* __restrict__ h,
                                                   const float* __restrict__ sraw,
                                                   const float* __restrict__ pw,
                                                   const float2* __restrict__ tmP,
                                                   float2* __restrict__ tmN,
                                                   float* __restrict__ zp,
                                                   const int kk) {
  __shared__ float s_sc[NPER];
  __shared__ float s_t[128];
  __shared__ unsigned char s_sel[128];
  __shared__ int s_rk[256];
  __shared__ float4 red4[512];
  __shared__ float s_norm;
  const int b = blockIdx.x;
  const int g = b >> 2;
  const int q = b & 3;
  const int tid = threadIdx.x;
  const int lane = tid & 63;

  if (tid < 64) {
    const float v0 = pw[lane], v1 = pw[lane + 64];
    float p = v0 * v0 + v1 * v1;
#pragma unroll
    for (int o = 32; o > 0; o >>= 1) p += __shfl_down(p, o);
    if (lane == 0) s_norm = 1.f / (sqrtf(p) + 1e-16f);
  }
  __syncthreads();
  const float inv_norm = s_norm;
#pragma unroll
  for (int i = 0; i < 2; ++i) {
    const int n = tid + i * 256;
    const int node = g * NPER + n;
    s_sc[n] = (tmP[node].x != 0.f) ? sraw[node] * inv_norm : -INFINITY;
  }
  __syncthreads();

  {
    const int n = q * 128 + (tid & 127);
    const int jb = (tid >> 7) * 256;
    const float s = s_sc[n];
    int rank = 0;
    for (int j = jb; j < jb + 256; ++j) {
      const float sj = s_sc[j];
      rank += (sj > s || (sj == s && j < n)) ? 1 : 0;
    }
    s_rk[tid] = rank;
  }
  __syncthreads();
  if (tid < 128) {
    const int n = q * 128 + tid;
    const int rank = s_rk[tid] + s_rk[tid + 128];
    const int sel = (rank < kk) ? 1 : 0;
    const float s = s_sc[n];
    const float t = sel ? tanhf(s) : 0.f;
    tmN[g * NPER + n] = make_float2(sel ? 1.f : 0.f, t);
    s_sel[tid] = (unsigned char)sel;
    s_t[tid] = t;
  }
  __syncthreads();

  const int c = tid & 31;
  const int r = tid >> 5;
  float4 pmax = make_float4(-INFINITY, -INFINITY, -INFINITY, -INFINITY);
  float4 psum = make_float4(0.f, 0.f, 0.f, 0.f);
  const size_t nbase = (size_t)g * NPER + q * 128;
  const float4* h4 = (const float4*)h;
  for (int i = 0; i < 16; ++i) {
    const int nl = r + 8 * i;
    if (s_sel[nl]) {
      float4 v = h4[(nbase + nl) * 32 + c];
      const float t = s_t[nl];
      v.x *= t; v.y *= t; v.z *= t; v.w *= t;
      pmax.x = fmaxf(pmax.x, v.x);
      pmax.y = fmaxf(pmax.y, v.y);
      pmax.z = fmaxf(pmax.z, v.z);
      pmax.w = fmaxf(pmax.w, v.w);
      psum.x += v.x; psum.y += v.y; psum.z += v.z; psum.w += v.w;
    }
  }
  red4[r * 32 + c] = pmax;
  red4[256 + r * 32 + c] = psum;
  __syncthreads();
  if (tid < 32) {
    float4 m = red4[tid];
    float4 sm = red4[256 + tid];
#pragma unroll
    for (int rr = 1; rr < 8; ++rr) {
      const float4 a = red4[rr * 32 + tid];
      const float4 s2 = red4[256 + rr * 32 + tid];
      m.x = fmaxf(m.x, a.x); m.y = fmaxf(m.y, a.y);
      m.z = fmaxf(m.z, a.z); m.w = fmaxf(m.w, a.w);
      sm.x += s2.x; sm.y += s2.y; sm.z += s2.z; sm.w += s2.w;
    }
    *(float4*)(zp + (size_t)b * 256 + tid * 4) = m;
    *(float4*)(zp + (size_t)b * 256 + 128 + tid * 4) = sm;
  }
}

// ---------------- MLP head (reduces 4 partials/graph/layer) ----------------

__global__ __launch_bounds__(128) void mlp_kernel(const float* __restrict__ zpart,
                                                  const float* __restrict__ w1,
                                                  const float* __restrict__ b1,
                                                  const float* __restrict__ w2,
                                                  const float* __restrict__ b2,
                                                  const float* __restrict__ w3,
                                                  const float* __restrict__ b3,
                                                  float* __restrict__ out,
                                                  const float ik0, const float ik1,
                                                  const float ik2) {
  __shared__ float z[256];
  __shared__ float h1[128];
  __shared__ float h2[64];
  const int g = blockIdx.x;
  const int t = threadIdx.x;
  const float iks[3] = {ik0, ik1, ik2};
  float zmax = 0.f, zmean = 0.f;
#pragma unroll
  for (int l = 0; l < 3; ++l) {
    const float* zp = zpart + ((size_t)l * 512 + g * 4) * 256;
    zmax += fmaxf(fmaxf(zp[t], zp[256 + t]), fmaxf(zp[512 + t], zp[768 + t]));
    zmean += (zp[128 + t] + zp[384 + t] + zp[640 + t] + zp[896 + t]) * iks[l];
  }
  z[t] = zmax;
  z[128 + t] = zmean;
  __syncthreads();
  float a = b1[t];
  for (int k = 0; k < 256; ++k) a = fmaf(z[k], w1[t * 256 + k], a);
  h1[t] = fmaxf(a, 0.f);
  __syncthreads();
  if (t < 64) {
    float a2 = b2[t];
    for (int k = 0; k < 128; ++k) a2 = fmaf(h1[k], w2[t * 128 + k], a2);
    h2[t] = fmaxf(a2, 0.f);
  }
  __syncthreads();
  if (t == 0) {
    float a3 = b3[0];
    for (int k = 0; k < 64; ++k) a3 = fmaf(h2[k], w3[k], a3);
    out[g] = 1.f / (1.f + expf(-a3));
  }
}

// ---------------- launch ----------------

extern "C" void kernel_launch(void* const* d_in, const int* in_sizes, int n_in,
                              void* d_out, int out_size, void* d_ws, size_t ws_size,
                              hipStream_t stream) {
  (void)in_sizes; (void)n_in; (void)out_size; (void)ws_size;
  const float* x_in = (const float*)d_in[0];
  const int* ei = (const int*)d_in[1];
  const float* wl[3] = {(const float*)d_in[2], (const float*)d_in[6], (const float*)d_in[10]};
  const float* cbl[3] = {(const float*)d_in[3], (const float*)d_in[7], (const float*)d_in[11]};
  const float* wr[3] = {(const float*)d_in[4], (const float*)d_in[8], (const float*)d_in[12]};
  const float* pw[3] = {(const float*)d_in[5], (const float*)d_in[9], (const float*)d_in[13]};
  const float* l1w = (const float*)d_in[14];
  const float* l1b = (const float*)d_in[15];
  const float* l2w = (const float*)d_in[16];
  const float* l2b = (const float*)d_in[17];
  const float* l3w = (const float*)d_in[18];
  const float* l3b = (const float*)d_in[19];
  float* out = (float*)d_out;

  char* w = (char*)d_ws;
  int* counts = (int*)(w + 0 * (1 << 20));  // dead after setup
  int* off = (int*)(w + 1 * (1 << 20));
  int* cursor = (int*)(w + 2 * (1 << 20));  // dead after scatter
  float* sraw = (float*)(w + 2 * (1 << 20));  // reuses cursor (256KB)
  float2* tmA = (float2*)(w + 3 * (1 << 20));              // 512KB
  float2* tmB = (float2*)(w + 3 * (1 << 20) + (1 << 19));  // 512KB
  float* zpart = (float*)(w + 4 * (1 << 20));              // 1.5MB (4..5.5MB)
  unsigned short* Whi = (unsigned short*)(w + 5 * (1 << 20) + (1 << 19));      // 192KB
  unsigned short* Wlo = (unsigned short*)(w + 5 * (1 << 20) + 3 * (1 << 18));  // 192KB
  int* ssrc = (int*)(w + 6 * (1 << 20));               // 2MB
  float* hA = (float*)(w + (size_t)40 * (1 << 20));    // 32MB
  float* hB = (float*)(w + (size_t)72 * (1 << 20));    // 32MB (total 104MB)

  init_kernel<<<NND / 256, 256, 0, stream>>>(counts, tmA);
  hist_kernel<<<NED / 256, 256, 0, stream>>>(ei, counts);
  scan_kernel<<<1, 1024, 0, stream>>>(counts, off, cursor);
  scatter_kernel<<<NED / 256, 256, 0, stream>>>(ei, cursor, ssrc);
  prepw_kernel<<<384, 256, 0, stream>>>(wl[0], wr[0], wl[1], wr[1], wl[2], wr[2], Whi, Wlo);

  const int ks[3] = {410, 328, 263};
  const float* xl = x_in;
  float* houts[3] = {hA, hB, hA};
  float2* tprev[3] = {tmA, tmB, tmA};
  float2* tnext[3] = {tmB, tmA, tmB};
  for (int l = 0; l < 3; ++l) {
    float* hout = houts[l];
    if (l == 0) {
      layer_kernel_t<1><<<1024, 256, 0, stream>>>(xl, tprev[l], off, ssrc,
                                                  Whi + (size_t)l * 32768,
                                                  Wlo + (size_t)l * 32768, cbl[l], pw[l],
                                                  hout, sraw);
    } else {
      layer_kernel_t<0><<<1024, 256, 0, stream>>>(xl, tprev[l], off, ssrc,
                                                  Whi + (size_t)l * 32768,
                                                  Wlo + (size_t)l * 32768, cbl[l], pw[l],
                                                  hout, sraw);
    }
    pool_kernel<<<NGR * 4, 256, 0, stream>>>(hout, sraw, pw[l], tprev[l], tnext[l],
                                             zpart + (size_t)l * 512 * 256, ks[l]);
    xl = hout;
  }
  mlp_kernel<<<NGR, 128, 0, stream>>>(zpart, l1w, l1b, l2w, l2b, l3w, l3b, out,
                                      1.f / 410.f, 1.f / 328.f, 1.f / 263.f);
}